// Round 1
// baseline (3450.301 us; speedup 1.0000x reference)
//
#include <hip/hip_runtime.h>

#define USER_NUM 100000
#define ITEM_NUM 200000
#define N_NODES  300000
#define N_EDGES  1250000
#define EMB      64

constexpr int TOTAL_F4 = N_NODES * EMB / 4;   // 4,800,000 float4 elements
constexpr int USER_F4  = USER_NUM * EMB / 4;  // 1,600,000

// out = ego = concat(user, item)
__global__ void lgcn_init_kernel(const float4* __restrict__ u, const float4* __restrict__ it,
                                 float4* __restrict__ out, float4* __restrict__ ego) {
    for (int i = blockIdx.x * blockDim.x + threadIdx.x; i < TOTAL_F4;
         i += gridDim.x * blockDim.x) {
        float4 v = (i < USER_F4) ? u[i] : it[i - USER_F4];
        out[i] = v;
        ego[i] = v;
    }
}

// y[rows[e]] += vals[e] * x[cols[e]]  (y pre-zeroed); 16 threads per edge, float4 each
__global__ void lgcn_spmm_kernel(const float* __restrict__ x, const float* __restrict__ vals,
                                 const int* __restrict__ rows, const int* __restrict__ cols,
                                 float* __restrict__ y) {
    int gid = blockIdx.x * blockDim.x + threadIdx.x;
    int e = gid >> 4;
    if (e >= N_EDGES) return;
    int t = gid & 15;
    int r = rows[e];
    int c = cols[e];
    float v = vals[e];
    float4 xv = *reinterpret_cast<const float4*>(x + (size_t)c * EMB + t * 4);
    float* yp = y + (size_t)r * EMB + t * 4;
    unsafeAtomicAdd(yp + 0, v * xv.x);
    unsafeAtomicAdd(yp + 1, v * xv.y);
    unsafeAtomicAdd(yp + 2, v * xv.z);
    unsafeAtomicAdd(yp + 3, v * xv.w);
}

// out += nxt
__global__ void lgcn_accum_kernel(float4* __restrict__ out, const float4* __restrict__ nxt) {
    for (int i = blockIdx.x * blockDim.x + threadIdx.x; i < TOTAL_F4;
         i += gridDim.x * blockDim.x) {
        float4 o = out[i];
        float4 n = nxt[i];
        o.x += n.x; o.y += n.y; o.z += n.z; o.w += n.w;
        out[i] = o;
    }
}

// out = (out + nxt) * 0.25f   (final layer, fused scale)
__global__ void lgcn_accum_scale_kernel(float4* __restrict__ out, const float4* __restrict__ nxt) {
    for (int i = blockIdx.x * blockDim.x + threadIdx.x; i < TOTAL_F4;
         i += gridDim.x * blockDim.x) {
        float4 o = out[i];
        float4 n = nxt[i];
        o.x = (o.x + n.x) * 0.25f;
        o.y = (o.y + n.y) * 0.25f;
        o.z = (o.z + n.z) * 0.25f;
        o.w = (o.w + n.w) * 0.25f;
        out[i] = o;
    }
}

extern "C" void kernel_launch(void* const* d_in, const int* in_sizes, int n_in,
                              void* d_out, int out_size, void* d_ws, size_t ws_size,
                              hipStream_t stream) {
    const float* u    = (const float*)d_in[0];
    const float* it   = (const float*)d_in[1];
    const float* vals = (const float*)d_in[2];
    const int*   rows = (const int*)d_in[3];
    const int*   cols = (const int*)d_in[4];
    float* out = (float*)d_out;

    const size_t nelem = (size_t)N_NODES * EMB;       // 19.2M floats
    const size_t nb    = nelem * sizeof(float);       // 76.8 MB

    if (ws_size < 2 * nb) return;  // need two ping-pong buffers; fail loudly if absent

    float* egoA = (float*)d_ws;
    float* egoB = egoA + nelem;

    lgcn_init_kernel<<<2048, 256, 0, stream>>>((const float4*)u, (const float4*)it,
                                               (float4*)out, (float4*)egoA);

    const int spmm_threads = N_EDGES * 16;            // 20M
    const int spmm_blocks  = (spmm_threads + 255) / 256;

    float* cur = egoA;
    float* nxt = egoB;
    for (int l = 0; l < 3; ++l) {
        hipMemsetAsync(nxt, 0, nb, stream);
        lgcn_spmm_kernel<<<spmm_blocks, 256, 0, stream>>>(cur, vals, rows, cols, nxt);
        if (l < 2) {
            lgcn_accum_kernel<<<2048, 256, 0, stream>>>((float4*)out, (const float4*)nxt);
        } else {
            lgcn_accum_scale_kernel<<<2048, 256, 0, stream>>>((float4*)out, (const float4*)nxt);
        }
        float* tmp = cur; cur = nxt; nxt = tmp;
    }
}

// Round 3
// 559.648 us; speedup vs baseline: 6.1651x; 6.1651x over previous
//
#include <hip/hip_runtime.h>

#define USER_NUM 100000
#define ITEM_NUM 200000
#define N_NODES  300000
#define N_EDGES  1250000
#define EMB      64

constexpr int TOTAL_F4 = N_NODES * EMB / 4;   // 4,800,000 float4
constexpr int USER_F4  = USER_NUM * EMB / 4;  // 1,600,000
constexpr int SCAN_CHUNK = 1024;              // elements per scanA block
constexpr int NBLK = (N_NODES + SCAN_CHUNK - 1) / SCAN_CHUNK;  // 293

// out = ego = concat(user, item)
__global__ void lgcn_init_kernel(const float4* __restrict__ u, const float4* __restrict__ it,
                                 float4* __restrict__ out, float4* __restrict__ ego) {
    for (int i = blockIdx.x * blockDim.x + threadIdx.x; i < TOTAL_F4;
         i += gridDim.x * blockDim.x) {
        float4 v = (i < USER_F4) ? u[i] : it[i - USER_F4];
        out[i] = v;
        ego[i] = v;
    }
}

// ---------------- CSR build ----------------

__global__ void hist_kernel(const int* __restrict__ rows, int* __restrict__ deg) {
    for (int e = blockIdx.x * blockDim.x + threadIdx.x; e < N_EDGES;
         e += gridDim.x * blockDim.x)
        atomicAdd(&deg[rows[e]], 1);
}

// in-place: deg -> per-element exclusive prefix within each 1024-chunk; bsum[b] = chunk total
__global__ void scanA_kernel(int* __restrict__ deg, int* __restrict__ bsum) {
    __shared__ int s[256];
    int tid = threadIdx.x;
    int base = blockIdx.x * SCAN_CHUNK + tid * 4;
    int v[4];
#pragma unroll
    for (int k = 0; k < 4; ++k) v[k] = (base + k < N_NODES) ? deg[base + k] : 0;
    int tsum = v[0] + v[1] + v[2] + v[3];
    int val = tsum;
    s[tid] = val;
    __syncthreads();
    for (int off = 1; off < 256; off <<= 1) {
        int t = (tid >= off) ? s[tid - off] : 0;
        __syncthreads();
        val += t;
        s[tid] = val;
        __syncthreads();
    }
    if (tid == 255) bsum[blockIdx.x] = val;
    int run = val - tsum;  // exclusive prefix of this thread's 4
#pragma unroll
    for (int k = 0; k < 4; ++k) {
        if (base + k < N_NODES) deg[base + k] = run;
        run += v[k];
    }
}

// in-place exclusive scan of the NBLK chunk sums (single block, 512 threads)
__global__ void scanB_kernel(int* __restrict__ bsum) {
    __shared__ int s[512];
    int tid = threadIdx.x;
    int v = (tid < NBLK) ? bsum[tid] : 0;
    int val = v;
    s[tid] = val;
    __syncthreads();
    for (int off = 1; off < 512; off <<= 1) {
        int t = (tid >= off) ? s[tid - off] : 0;
        __syncthreads();
        val += t;
        s[tid] = val;
        __syncthreads();
    }
    if (tid < NBLK) bsum[tid] = val - v;
}

// rowptr[i] = wr[i] = pre[i] + boff[i/1024]; rowptr[N] = N_EDGES
__global__ void scanC_kernel(const int* __restrict__ pre, const int* __restrict__ boff,
                             int* __restrict__ rowptr, int* __restrict__ wr) {
    int i = blockIdx.x * blockDim.x + threadIdx.x;
    if (i < N_NODES) {
        int p = pre[i] + boff[i / SCAN_CHUNK];
        rowptr[i] = p;
        wr[i] = p;
    }
    if (i == 0) rowptr[N_NODES] = N_EDGES;
}

__global__ void scatter_kernel(const int* __restrict__ rows, const int* __restrict__ cols,
                               const float* __restrict__ vals, int* __restrict__ wr,
                               int* __restrict__ pcols, float* __restrict__ pvals) {
    for (int e = blockIdx.x * blockDim.x + threadIdx.x; e < N_EDGES;
         e += gridDim.x * blockDim.x) {
        int r = rows[e];
        int p = atomicAdd(&wr[r], 1);
        pcols[p] = cols[e];
        pvals[p] = vals[e];
    }
}

// ---------------- CSR SpMM (gather), fused with accumulate ----------------
// 16 lanes per row, one float4 per lane.  MODE 0: nxt = A*x, out += nxt.
//                                         MODE 1: out = (out + A*x) * 0.25 (no nxt).
template <int MODE>
__global__ void spmm_csr_kernel(const float4* __restrict__ x, const int* __restrict__ rowptr,
                                const int* __restrict__ pcols, const float* __restrict__ pvals,
                                float4* __restrict__ nxt, float4* __restrict__ out) {
    int gid = blockIdx.x * blockDim.x + threadIdx.x;
    int row = gid >> 4;
    if (row >= N_NODES) return;
    int t = gid & 15;
    int beg = rowptr[row];
    int end = rowptr[row + 1];
    float4 acc = {0.f, 0.f, 0.f, 0.f};
    for (int i = beg; i < end; ++i) {
        int c = pcols[i];
        float v = pvals[i];
        float4 xv = x[c * 16 + t];
        acc.x += v * xv.x;
        acc.y += v * xv.y;
        acc.z += v * xv.z;
        acc.w += v * xv.w;
    }
    int oi = row * 16 + t;
    float4 o = out[oi];
    if (MODE == 0) {
        nxt[oi] = acc;
        o.x += acc.x; o.y += acc.y; o.z += acc.z; o.w += acc.w;
    } else {
        o.x = (o.x + acc.x) * 0.25f;
        o.y = (o.y + acc.y) * 0.25f;
        o.z = (o.z + acc.z) * 0.25f;
        o.w = (o.w + acc.w) * 0.25f;
    }
    out[oi] = o;
}

// ---------------- fallback (round-1 atomic path) ----------------

__global__ void lgcn_spmm_atomic_kernel(const float* __restrict__ x, const float* __restrict__ vals,
                                        const int* __restrict__ rows, const int* __restrict__ cols,
                                        float* __restrict__ y) {
    int gid = blockIdx.x * blockDim.x + threadIdx.x;
    int e = gid >> 4;
    if (e >= N_EDGES) return;
    int t = gid & 15;
    int r = rows[e];
    int c = cols[e];
    float v = vals[e];
    float4 xv = *reinterpret_cast<const float4*>(x + (size_t)c * EMB + t * 4);
    float* yp = y + (size_t)r * EMB + t * 4;
    unsafeAtomicAdd(yp + 0, v * xv.x);
    unsafeAtomicAdd(yp + 1, v * xv.y);
    unsafeAtomicAdd(yp + 2, v * xv.z);
    unsafeAtomicAdd(yp + 3, v * xv.w);
}

__global__ void lgcn_accum_kernel(float4* __restrict__ out, const float4* __restrict__ nxt) {
    for (int i = blockIdx.x * blockDim.x + threadIdx.x; i < TOTAL_F4;
         i += gridDim.x * blockDim.x) {
        float4 o = out[i], n = nxt[i];
        o.x += n.x; o.y += n.y; o.z += n.z; o.w += n.w;
        out[i] = o;
    }
}

__global__ void lgcn_accum_scale_kernel(float4* __restrict__ out, const float4* __restrict__ nxt) {
    for (int i = blockIdx.x * blockDim.x + threadIdx.x; i < TOTAL_F4;
         i += gridDim.x * blockDim.x) {
        float4 o = out[i], n = nxt[i];
        o.x = (o.x + n.x) * 0.25f;
        o.y = (o.y + n.y) * 0.25f;
        o.z = (o.z + n.z) * 0.25f;
        o.w = (o.w + n.w) * 0.25f;
        out[i] = o;
    }
}

extern "C" void kernel_launch(void* const* d_in, const int* in_sizes, int n_in,
                              void* d_out, int out_size, void* d_ws, size_t ws_size,
                              hipStream_t stream) {
    const float* u    = (const float*)d_in[0];
    const float* it   = (const float*)d_in[1];
    const float* vals = (const float*)d_in[2];
    const int*   rows = (const int*)d_in[3];
    const int*   cols = (const int*)d_in[4];
    float* out = (float*)d_out;

    const size_t nelem = (size_t)N_NODES * EMB;   // 19.2M floats
    const size_t nb    = nelem * sizeof(float);   // 76.8 MB

    auto align256 = [](size_t x) { return (x + 255) & ~(size_t)255; };

    // workspace layout
    size_t off = 0;
    float* egoA = (float*)((char*)d_ws + off); off += align256(nb);
    float* egoB = (float*)((char*)d_ws + off); off += align256(nb);
    size_t csr_base = off;
    int*   deg    = (int*)((char*)d_ws + off); off += align256((size_t)N_NODES * 4);
    int*   bsum   = (int*)((char*)d_ws + off); off += align256(512 * 4);
    int*   rowptr = (int*)((char*)d_ws + off); off += align256((size_t)(N_NODES + 1) * 4);
    int*   wr     = (int*)((char*)d_ws + off); off += align256((size_t)N_NODES * 4);
    int*   pcols  = (int*)((char*)d_ws + off); off += align256((size_t)N_EDGES * 4);
    float* pvals  = (float*)((char*)d_ws + off); off += align256((size_t)N_EDGES * 4);
    bool have_csr = (ws_size >= off);
    (void)csr_base;

    if (ws_size < 2 * nb) return;  // cannot run at all

    lgcn_init_kernel<<<2048, 256, 0, stream>>>((const float4*)u, (const float4*)it,
                                               (float4*)out, (float4*)egoA);

    if (have_csr) {
        hipMemsetAsync(deg, 0, (size_t)N_NODES * 4, stream);
        hist_kernel<<<1024, 256, 0, stream>>>(rows, deg);
        scanA_kernel<<<NBLK, 256, 0, stream>>>(deg, bsum);
        scanB_kernel<<<1, 512, 0, stream>>>(bsum);
        scanC_kernel<<<(N_NODES + 255) / 256, 256, 0, stream>>>(deg, bsum, rowptr, wr);
        scatter_kernel<<<1024, 256, 0, stream>>>(rows, cols, vals, wr, pcols, pvals);

        const int spmm_blocks = (N_NODES * 16 + 255) / 256;  // 18750
        // layer 0: egoA -> egoB, out += egoB
        spmm_csr_kernel<0><<<spmm_blocks, 256, 0, stream>>>(
            (const float4*)egoA, rowptr, pcols, pvals, (float4*)egoB, (float4*)out);
        // layer 1: egoB -> egoA, out += egoA
        spmm_csr_kernel<0><<<spmm_blocks, 256, 0, stream>>>(
            (const float4*)egoB, rowptr, pcols, pvals, (float4*)egoA, (float4*)out);
        // layer 2: egoA -> (none), out = (out + A*egoA) * 0.25
        spmm_csr_kernel<1><<<spmm_blocks, 256, 0, stream>>>(
            (const float4*)egoA, rowptr, pcols, pvals, nullptr, (float4*)out);
    } else {
        const int spmm_threads = N_EDGES * 16;
        const int spmm_blocks  = (spmm_threads + 255) / 256;
        float* cur = egoA;
        float* nxt = egoB;
        for (int l = 0; l < 3; ++l) {
            hipMemsetAsync(nxt, 0, nb, stream);
            lgcn_spmm_atomic_kernel<<<spmm_blocks, 256, 0, stream>>>(cur, vals, rows, cols, nxt);
            if (l < 2)
                lgcn_accum_kernel<<<2048, 256, 0, stream>>>((float4*)out, (const float4*)nxt);
            else
                lgcn_accum_scale_kernel<<<2048, 256, 0, stream>>>((float4*)out, (const float4*)nxt);
            float* tmp = cur; cur = nxt; nxt = tmp;
        }
    }
}

// Round 6
// 478.041 us; speedup vs baseline: 7.2176x; 1.1707x over previous
//
#include <hip/hip_runtime.h>

#define USER_NUM 100000
#define ITEM_NUM 200000
#define N_NODES  300000
#define N_EDGES  1250000
#define EMB      64

constexpr int USER_F4  = USER_NUM * EMB / 4;  // 1,600,000 float4 in user part
constexpr int SCAN_CHUNK = 1024;
constexpr int NBLK = (N_NODES + SCAN_CHUNK - 1) / SCAN_CHUNK;  // 293

typedef float f32x4 __attribute__((ext_vector_type(4)));

__device__ __forceinline__ void nt_store_f4(const float4& v, float4* p) {
    f32x4 nv = {v.x, v.y, v.z, v.w};
    __builtin_nontemporal_store(nv, reinterpret_cast<f32x4*>(p));
}

// ---------------- CSR build ----------------

__global__ void hist_kernel(const int* __restrict__ rows, int* __restrict__ deg) {
    for (int e = blockIdx.x * blockDim.x + threadIdx.x; e < N_EDGES;
         e += gridDim.x * blockDim.x)
        atomicAdd(&deg[rows[e]], 1);
}

// in-place: deg -> per-element exclusive prefix within each 1024-chunk; bsum[b] = chunk total
__global__ void scanA_kernel(int* __restrict__ deg, int* __restrict__ bsum) {
    __shared__ int s[256];
    int tid = threadIdx.x;
    int base = blockIdx.x * SCAN_CHUNK + tid * 4;
    int v[4];
#pragma unroll
    for (int k = 0; k < 4; ++k) v[k] = (base + k < N_NODES) ? deg[base + k] : 0;
    int tsum = v[0] + v[1] + v[2] + v[3];
    int val = tsum;
    s[tid] = val;
    __syncthreads();
    for (int off = 1; off < 256; off <<= 1) {
        int t = (tid >= off) ? s[tid - off] : 0;
        __syncthreads();
        val += t;
        s[tid] = val;
        __syncthreads();
    }
    if (tid == 255) bsum[blockIdx.x] = val;
    int run = val - tsum;
#pragma unroll
    for (int k = 0; k < 4; ++k) {
        if (base + k < N_NODES) deg[base + k] = run;
        run += v[k];
    }
}

__global__ void scanB_kernel(int* __restrict__ bsum) {
    __shared__ int s[512];
    int tid = threadIdx.x;
    int v = (tid < NBLK) ? bsum[tid] : 0;
    int val = v;
    s[tid] = val;
    __syncthreads();
    for (int off = 1; off < 512; off <<= 1) {
        int t = (tid >= off) ? s[tid - off] : 0;
        __syncthreads();
        val += t;
        s[tid] = val;
        __syncthreads();
    }
    if (tid < NBLK) bsum[tid] = val - v;
}

__global__ void scanC_kernel(const int* __restrict__ pre, const int* __restrict__ boff,
                             int* __restrict__ rowptr, int* __restrict__ wr) {
    int i = blockIdx.x * blockDim.x + threadIdx.x;
    if (i < N_NODES) {
        int p = pre[i] + boff[i / SCAN_CHUNK];
        rowptr[i] = p;
        wr[i] = p;
    }
    if (i == 0) rowptr[N_NODES] = N_EDGES;
}

// pack (col, val-bits) into one int2 -> single 8B random store per edge
__global__ void scatter_kernel(const int* __restrict__ rows, const int* __restrict__ cols,
                               const float* __restrict__ vals, int* __restrict__ wr,
                               int2* __restrict__ pedge) {
    for (int e = blockIdx.x * blockDim.x + threadIdx.x; e < N_EDGES;
         e += gridDim.x * blockDim.x) {
        int r = rows[e];
        int p = atomicAdd(&wr[r], 1);
        int2 pk;
        pk.x = cols[e];
        pk.y = __float_as_int(vals[e]);
        pedge[p] = pk;
    }
}

// ---------------- SpMM kernels (gather form, 16 lanes/row, float4/lane) ----------------

// layer 0: gather directly from split (u, it) inputs; write y only.
__global__ void spmm_first_kernel(const float4* __restrict__ u, const float4* __restrict__ it,
                                  const int* __restrict__ rowptr, const int2* __restrict__ pedge,
                                  float4* __restrict__ y) {
    int gid = blockIdx.x * blockDim.x + threadIdx.x;
    int row = gid >> 4;
    if (row >= N_NODES) return;
    int t = gid & 15;
    int beg = rowptr[row], end = rowptr[row + 1];
    float4 a0 = {0.f, 0.f, 0.f, 0.f}, a1 = {0.f, 0.f, 0.f, 0.f};
    int i = beg;
    for (; i + 1 < end; i += 2) {
        int2 e0 = pedge[i], e1 = pedge[i + 1];
        const float4* p0 = (e0.x < USER_NUM) ? (u + e0.x * 16 + t) : (it + (e0.x - USER_NUM) * 16 + t);
        const float4* p1 = (e1.x < USER_NUM) ? (u + e1.x * 16 + t) : (it + (e1.x - USER_NUM) * 16 + t);
        float4 x0 = *p0, x1 = *p1;
        float v0 = __int_as_float(e0.y), v1 = __int_as_float(e1.y);
        a0.x += v0 * x0.x; a0.y += v0 * x0.y; a0.z += v0 * x0.z; a0.w += v0 * x0.w;
        a1.x += v1 * x1.x; a1.y += v1 * x1.y; a1.z += v1 * x1.z; a1.w += v1 * x1.w;
    }
    if (i < end) {
        int2 e0 = pedge[i];
        const float4* p0 = (e0.x < USER_NUM) ? (u + e0.x * 16 + t) : (it + (e0.x - USER_NUM) * 16 + t);
        float4 x0 = *p0;
        float v0 = __int_as_float(e0.y);
        a0.x += v0 * x0.x; a0.y += v0 * x0.y; a0.z += v0 * x0.z; a0.w += v0 * x0.w;
    }
    float4 acc = {a0.x + a1.x, a0.y + a1.y, a0.z + a1.z, a0.w + a1.w};
    nt_store_f4(acc, &y[row * 16 + t]);
}

// middle layer: gather from x; write y only.
__global__ void spmm_mid_kernel(const float4* __restrict__ x, const int* __restrict__ rowptr,
                                const int2* __restrict__ pedge, float4* __restrict__ y) {
    int gid = blockIdx.x * blockDim.x + threadIdx.x;
    int row = gid >> 4;
    if (row >= N_NODES) return;
    int t = gid & 15;
    int beg = rowptr[row], end = rowptr[row + 1];
    float4 a0 = {0.f, 0.f, 0.f, 0.f}, a1 = {0.f, 0.f, 0.f, 0.f};
    int i = beg;
    for (; i + 1 < end; i += 2) {
        int2 e0 = pedge[i], e1 = pedge[i + 1];
        float4 x0 = x[e0.x * 16 + t];
        float4 x1 = x[e1.x * 16 + t];
        float v0 = __int_as_float(e0.y), v1 = __int_as_float(e1.y);
        a0.x += v0 * x0.x; a0.y += v0 * x0.y; a0.z += v0 * x0.z; a0.w += v0 * x0.w;
        a1.x += v1 * x1.x; a1.y += v1 * x1.y; a1.z += v1 * x1.z; a1.w += v1 * x1.w;
    }
    if (i < end) {
        int2 e0 = pedge[i];
        float4 x0 = x[e0.x * 16 + t];
        float v0 = __int_as_float(e0.y);
        a0.x += v0 * x0.x; a0.y += v0 * x0.y; a0.z += v0 * x0.z; a0.w += v0 * x0.w;
    }
    float4 acc = {a0.x + a1.x, a0.y + a1.y, a0.z + a1.z, a0.w + a1.w};
    nt_store_f4(acc, &y[row * 16 + t]);
}

// last layer: e3 = A*x (x holds e2); out = (ego + e1 + e2 + e3) * 0.25
__global__ void spmm_last_kernel(const float4* __restrict__ x,     // e2
                                 const float4* __restrict__ e1,
                                 const float4* __restrict__ u, const float4* __restrict__ it,
                                 const int* __restrict__ rowptr, const int2* __restrict__ pedge,
                                 float4* __restrict__ out) {
    int gid = blockIdx.x * blockDim.x + threadIdx.x;
    int row = gid >> 4;
    if (row >= N_NODES) return;
    int t = gid & 15;
    int beg = rowptr[row], end = rowptr[row + 1];
    float4 a0 = {0.f, 0.f, 0.f, 0.f}, a1 = {0.f, 0.f, 0.f, 0.f};
    int i = beg;
    for (; i + 1 < end; i += 2) {
        int2 e0 = pedge[i], ee1 = pedge[i + 1];
        float4 x0 = x[e0.x * 16 + t];
        float4 x1 = x[ee1.x * 16 + t];
        float v0 = __int_as_float(e0.y), v1 = __int_as_float(ee1.y);
        a0.x += v0 * x0.x; a0.y += v0 * x0.y; a0.z += v0 * x0.z; a0.w += v0 * x0.w;
        a1.x += v1 * x1.x; a1.y += v1 * x1.y; a1.z += v1 * x1.z; a1.w += v1 * x1.w;
    }
    if (i < end) {
        int2 e0 = pedge[i];
        float4 x0 = x[e0.x * 16 + t];
        float v0 = __int_as_float(e0.y);
        a0.x += v0 * x0.x; a0.y += v0 * x0.y; a0.z += v0 * x0.z; a0.w += v0 * x0.w;
    }
    int oi = row * 16 + t;
    float4 ego = (oi < USER_F4) ? u[oi] : it[oi - USER_F4];
    float4 p1 = e1[oi];
    float4 p2 = x[oi];
    float4 o;
    o.x = (ego.x + p1.x + p2.x + a0.x + a1.x) * 0.25f;
    o.y = (ego.y + p1.y + p2.y + a0.y + a1.y) * 0.25f;
    o.z = (ego.z + p1.z + p2.z + a0.z + a1.z) * 0.25f;
    o.w = (ego.w + p1.w + p2.w + a0.w + a1.w) * 0.25f;
    nt_store_f4(o, &out[oi]);
}

extern "C" void kernel_launch(void* const* d_in, const int* in_sizes, int n_in,
                              void* d_out, int out_size, void* d_ws, size_t ws_size,
                              hipStream_t stream) {
    const float* u    = (const float*)d_in[0];
    const float* it   = (const float*)d_in[1];
    const float* vals = (const float*)d_in[2];
    const int*   rows = (const int*)d_in[3];
    const int*   cols = (const int*)d_in[4];
    float* out = (float*)d_out;

    const size_t nelem = (size_t)N_NODES * EMB;   // 19.2M floats
    const size_t nb    = nelem * sizeof(float);   // 76.8 MB

    auto align256 = [](size_t x) { return (x + 255) & ~(size_t)255; };

    size_t off = 0;
    float* bufA = (float*)((char*)d_ws + off); off += align256(nb);   // e2
    float* bufB = (float*)((char*)d_ws + off); off += align256(nb);   // e1
    int*   deg    = (int*)((char*)d_ws + off); off += align256((size_t)N_NODES * 4);
    int*   bsum   = (int*)((char*)d_ws + off); off += align256(512 * 4);
    int*   rowptr = (int*)((char*)d_ws + off); off += align256((size_t)(N_NODES + 1) * 4);
    int*   wr     = (int*)((char*)d_ws + off); off += align256((size_t)N_NODES * 4);
    int2*  pedge  = (int2*)((char*)d_ws + off); off += align256((size_t)N_EDGES * 8);

    if (ws_size < off) return;  // fail loudly (previous rounds confirm ws is larger)

    // CSR build (inputs are restored pristine before every timed call, so rebuild each call)
    (void)hipMemsetAsync(deg, 0, (size_t)N_NODES * 4, stream);
    hist_kernel<<<1024, 256, 0, stream>>>(rows, deg);
    scanA_kernel<<<NBLK, 256, 0, stream>>>(deg, bsum);
    scanB_kernel<<<1, 512, 0, stream>>>(bsum);
    scanC_kernel<<<(N_NODES + 255) / 256, 256, 0, stream>>>(deg, bsum, rowptr, wr);
    scatter_kernel<<<1024, 256, 0, stream>>>(rows, cols, vals, wr, pedge);

    const int spmm_blocks = (N_NODES * 16 + 255) / 256;  // 18750

    // e1 = A * ego  (gather straight from split inputs)
    spmm_first_kernel<<<spmm_blocks, 256, 0, stream>>>(
        (const float4*)u, (const float4*)it, rowptr, pedge, (float4*)bufB);
    // e2 = A * e1
    spmm_mid_kernel<<<spmm_blocks, 256, 0, stream>>>(
        (const float4*)bufB, rowptr, pedge, (float4*)bufA);
    // out = (ego + e1 + e2 + A*e2) / 4
    spmm_last_kernel<<<spmm_blocks, 256, 0, stream>>>(
        (const float4*)bufA, (const float4*)bufB,
        (const float4*)u, (const float4*)it, rowptr, pedge, (float4*)out);
}